// Round 3
// baseline (531.638 us; speedup 1.0000x reference)
//
#include <hip/hip_runtime.h>
#include <stdint.h>

// Problem constants (from reference): B=8, L=4096, D=1024, S=255
constexpr int kB = 8;
constexpr int kL = 4096;
constexpr int kD = 1024;
constexpr int kS = 255;
constexpr int kM = kB * kL;   // 32768 rows of A / out
constexpr int kK = 2 * kD;    // 2048 reduction dim
constexpr int kN = kD;        // 1024 output features

#define TILE_M 128
#define TILE_N 128
#define TILE_K 32
#define LDS_STRIDE 20   // dwords/row: reads spread over all 32 banks 2-way (free)

typedef __bf16 bf16x8 __attribute__((ext_vector_type(8)));
typedef float  f32x4  __attribute__((ext_vector_type(4)));

// fp32 pair -> packed bf16x2, round-half-up: add 0x8000, keep high halves via v_perm.
__device__ __forceinline__ uint32_t pk_bf16x2(float a, float b) {
    uint32_t ua = __float_as_uint(a) + 0x8000u;
    uint32_t ub = __float_as_uint(b) + 0x8000u;
    return __builtin_amdgcn_perm(ub, ua, 0x07060302u);
}

// C[m,n] = relu( sum_k A[m,k]*W[n,k] + bias[n] )
// A[m, k<1024]  = words[m*1024 + k]
// A[m, k>=1024] = smap[m]>=0 ? sents[(b*255+smap[m])*1024 + k-1024] : 0
__global__ __launch_bounds__(256)
void wsib_gemm(const float* __restrict__ words,
               const float* __restrict__ sents,
               const float* __restrict__ W,
               const float* __restrict__ bias,
               const int*   __restrict__ smap,
               float* __restrict__ out)
{
    // double-buffered bf16 tiles (packed dwords): 2 x 10 KiB each = 40 KiB total
    __shared__ uint32_t Asm[2][TILE_M * LDS_STRIDE];
    __shared__ uint32_t Bsm[2][TILE_N * LDS_STRIDE];

    const int tid = threadIdx.x;
    const int nT  = blockIdx.x;   // 0..7
    const int mT  = blockIdx.y;   // 0..255

    // ---- staging: each thread owns one (row, 16-float half) slice per k-step
    const int sRow = tid >> 1;          // 0..127
    const int half = tid & 1;           // which 16-float chunk of the 32-k tile
    const int mRow = mT * TILE_M + sRow;
    const int bIdx = mRow >> 12;        // / L (4096)
    const float* wsrc = words + (size_t)mRow * kD + half * 16;
    const int sidx = smap[mRow];
    const float* ssrc = (sidx >= 0)
        ? sents + ((size_t)bIdx * kS + sidx) * kD + half * 16
        : nullptr;
    const float* bsrc = W + (size_t)(nT * TILE_N + sRow) * kK + half * 16;
    const int dstOff = sRow * LDS_STRIDE + half * 8;

    // ---- compute: 4 waves in 2x2 grid, each wave 64x64 = 4x4 mfma 16x16 tiles
    const int lane = tid & 63;
    const int wv   = tid >> 6;
    const int wm   = (wv & 1) * 64;
    const int wn   = (wv >> 1) * 64;
    const int fr   = lane & 15;         // fragment row (m for A, n for B)
    const int quad = lane >> 4;         // k-quad

    f32x4 acc[4][4];
    #pragma unroll
    for (int i = 0; i < 4; ++i)
        #pragma unroll
        for (int j = 0; j < 4; ++j)
            acc[i][j] = (f32x4){0.f, 0.f, 0.f, 0.f};

    // ---- prologue: stage tile 0 into buffer 0 (k=0 is always words-side)
    float4 ra[4], rb[4];
    {
        const float4* pa = (const float4*)wsrc;
        const float4* pb = (const float4*)bsrc;
        #pragma unroll
        for (int i = 0; i < 4; ++i) { ra[i] = pa[i]; rb[i] = pb[i]; }
        uint32_t pa2[8], pb2[8];
        #pragma unroll
        for (int i = 0; i < 4; ++i) {
            pa2[2*i]   = pk_bf16x2(ra[i].x, ra[i].y);
            pa2[2*i+1] = pk_bf16x2(ra[i].z, ra[i].w);
            pb2[2*i]   = pk_bf16x2(rb[i].x, rb[i].y);
            pb2[2*i+1] = pk_bf16x2(rb[i].z, rb[i].w);
        }
        uint32_t* ad = &Asm[0][dstOff];
        uint32_t* bd = &Bsm[0][dstOff];
        ((uint4*)ad)[0] = make_uint4(pa2[0], pa2[1], pa2[2], pa2[3]);
        ((uint4*)ad)[1] = make_uint4(pa2[4], pa2[5], pa2[6], pa2[7]);
        ((uint4*)bd)[0] = make_uint4(pb2[0], pb2[1], pb2[2], pb2[3]);
        ((uint4*)bd)[1] = make_uint4(pb2[4], pb2[5], pb2[6], pb2[7]);
    }
    __syncthreads();

    int p = 0;
    for (int k0 = 0; k0 < kK; k0 += TILE_K) {
        const int k1 = k0 + TILE_K;
        const bool more = (k1 < kK);

        // ---- issue next tile's global loads first (longest latency)
        if (more) {
            const float* asrc = (k1 < kD) ? (wsrc + k1)
                                          : (ssrc ? (ssrc + (k1 - kD)) : nullptr);
            if (asrc) {
                const float4* pp = (const float4*)asrc;
                #pragma unroll
                for (int i = 0; i < 4; ++i) ra[i] = pp[i];
            } else {
                #pragma unroll
                for (int i = 0; i < 4; ++i) ra[i] = make_float4(0.f, 0.f, 0.f, 0.f);
            }
            const float4* pp = (const float4*)(bsrc + k1);
            #pragma unroll
            for (int i = 0; i < 4; ++i) rb[i] = pp[i];
        }

        // ---- fragments from buffer p (data ready since last barrier)
        bf16x8 af[4], bfv[4];
        #pragma unroll
        for (int mi = 0; mi < 4; ++mi) {
            int row = wm + mi * 16 + fr;
            af[mi] = *(const bf16x8*)&Asm[p][row * LDS_STRIDE + quad * 4];
        }
        #pragma unroll
        for (int ni = 0; ni < 4; ++ni) {
            int row = wn + ni * 16 + fr;
            bfv[ni] = *(const bf16x8*)&Bsm[p][row * LDS_STRIDE + quad * 4];
        }

        // ---- 16 MFMAs (covers the in-flight global loads)
        #pragma unroll
        for (int mi = 0; mi < 4; ++mi)
            #pragma unroll
            for (int ni = 0; ni < 4; ++ni)
                acc[mi][ni] = __builtin_amdgcn_mfma_f32_16x16x32_bf16(
                    af[mi], bfv[ni], acc[mi][ni], 0, 0, 0);

        // ---- pack + write next tile into the other buffer, single barrier
        if (more) {
            uint32_t pa2[8], pb2[8];
            #pragma unroll
            for (int i = 0; i < 4; ++i) {
                pa2[2*i]   = pk_bf16x2(ra[i].x, ra[i].y);
                pa2[2*i+1] = pk_bf16x2(ra[i].z, ra[i].w);
                pb2[2*i]   = pk_bf16x2(rb[i].x, rb[i].y);
                pb2[2*i+1] = pk_bf16x2(rb[i].z, rb[i].w);
            }
            uint32_t* ad = &Asm[p ^ 1][dstOff];
            uint32_t* bd = &Bsm[p ^ 1][dstOff];
            ((uint4*)ad)[0] = make_uint4(pa2[0], pa2[1], pa2[2], pa2[3]);
            ((uint4*)ad)[1] = make_uint4(pa2[4], pa2[5], pa2[6], pa2[7]);
            ((uint4*)bd)[0] = make_uint4(pb2[0], pb2[1], pb2[2], pb2[3]);
            ((uint4*)bd)[1] = make_uint4(pb2[4], pb2[5], pb2[6], pb2[7]);
            __syncthreads();   // writes to buf[p^1] done; reads of buf[p] done
        }
        p ^= 1;
    }

    // ---- epilogue: bias + relu, fp32 store
    // C/D layout (verified m89): col = lane&15, row = quad*4 + r
    const int rowBase = mT * TILE_M + wm;
    const int colBase = nT * TILE_N + wn;
    float bv[4];
    #pragma unroll
    for (int ni = 0; ni < 4; ++ni) bv[ni] = bias[colBase + ni * 16 + fr];

    #pragma unroll
    for (int mi = 0; mi < 4; ++mi) {
        #pragma unroll
        for (int ni = 0; ni < 4; ++ni) {
            const int col = colBase + ni * 16 + fr;
            #pragma unroll
            for (int r = 0; r < 4; ++r) {
                const int row = rowBase + mi * 16 + quad * 4 + r;
                float v = acc[mi][ni][r] + bv[ni];
                out[(size_t)row * kN + col] = fmaxf(v, 0.f);
            }
        }
    }
}

extern "C" void kernel_launch(void* const* d_in, const int* in_sizes, int n_in,
                              void* d_out, int out_size, void* d_ws, size_t ws_size,
                              hipStream_t stream) {
    const float* words = (const float*)d_in[0];   // [8, 4096, 1024] f32
    const float* sents = (const float*)d_in[1];   // [8, 255, 1024]  f32
    const float* W     = (const float*)d_in[2];   // [1024, 2048]    f32
    const float* bias  = (const float*)d_in[3];   // [1024]          f32
    const int*   smap  = (const int*)d_in[4];     // [8, 4096]       i32
    float* out = (float*)d_out;                   // [8, 4096, 1024] f32

    dim3 grid(kN / TILE_N, kM / TILE_M);          // (8, 256)
    wsib_gemm<<<grid, 256, 0, stream>>>(words, sents, W, bias, smap, out);
}

// Round 4
// 417.031 us; speedup vs baseline: 1.2748x; 1.2748x over previous
//
#include <hip/hip_runtime.h>
#include <stdint.h>

// Problem constants (from reference): B=8, L=4096, D=1024, S=255
constexpr int kB = 8;
constexpr int kL = 4096;
constexpr int kD = 1024;
constexpr int kS = 255;
constexpr int kM = kB * kL;   // 32768 rows of A / out
constexpr int kK = 2 * kD;    // 2048 reduction dim
constexpr int kN = kD;        // 1024 output features

#define TILE_M 128
#define TILE_N 128
#define TILE_K 32

typedef __bf16 bf16x8 __attribute__((ext_vector_type(8)));
typedef float  f32x4  __attribute__((ext_vector_type(4)));

// ---- workspace layout (bytes) ----
constexpr size_t WS_WORDS = 0;                                   // 33,554,432 bf16
constexpr size_t WS_SENTS = WS_WORDS + (size_t)kM * kD * 2;      // 67,108,864
constexpr size_t WS_W     = WS_SENTS + (size_t)kB * kS * kD * 2; // +4,177,920
constexpr size_t WS_ZP    = WS_W + (size_t)kN * kK * 2;          // +4,194,304
constexpr size_t WS_NEED  = WS_ZP + 3072;                        // zero page 3 KiB

// fp32 pair -> packed bf16x2, round-half-up (matches R1-R3 validated accuracy)
__device__ __forceinline__ uint32_t pk_bf16x2(float a, float b) {
    uint32_t ua = __float_as_uint(a) + 0x8000u;
    uint32_t ub = __float_as_uint(b) + 0x8000u;
    return __builtin_amdgcn_perm(ub, ua, 0x07060302u);
}

// async global->LDS 16B per lane: dest = wave-uniform base + lane*16
__device__ __forceinline__ void async16(const void* g, void* l) {
    __builtin_amdgcn_global_load_lds(
        (const __attribute__((address_space(1))) uint32_t*)g,
        (__attribute__((address_space(3))) uint32_t*)l, 16, 0, 0);
}

// ===================== prepass: fp32 -> bf16 conversion =====================
__global__ __launch_bounds__(256)
void cvt_prepass(const float4* __restrict__ words, const float4* __restrict__ sents,
                 const float4* __restrict__ W,
                 uint2* __restrict__ wordsB, uint2* __restrict__ sentsB,
                 uint2* __restrict__ WB, uint32_t* __restrict__ zp)
{
    constexpr size_t NW = (size_t)kM * kD / 4;       // 8,388,608
    constexpr size_t NS = (size_t)kB * kS * kD / 4;  //   522,240
    constexpr size_t NT = NW + NS + (size_t)kN * kK / 4;
    if (blockIdx.x == 0) {                            // zero page for invalid rows
        for (int t = threadIdx.x; t < 768; t += 256) zp[t] = 0u;
    }
    size_t i = (size_t)blockIdx.x * 256 + threadIdx.x;
    if (i >= NT) return;
    float4 v; uint2* dst;
    if (i < NW)            { v = words[i];            dst = wordsB + i; }
    else if (i < NW + NS)  { v = sents[i - NW];       dst = sentsB + (i - NW); }
    else                   { v = W[i - NW - NS];      dst = WB + (i - NW - NS); }
    uint2 o;
    o.x = pk_bf16x2(v.x, v.y);
    o.y = pk_bf16x2(v.z, v.w);
    *dst = o;
}

// ===================== main GEMM: m97 structure, bf16 in d_ws ===============
// C[m,n] = relu( sum_k A[m,k]*W[n,k] + bias[n] )
__global__ __launch_bounds__(256)
void wsib_gemm_bf(const uint8_t* __restrict__ wordsB,   // [32768][1024] bf16
                  const uint8_t* __restrict__ sentsB,   // [8*255][1024] bf16
                  const uint8_t* __restrict__ WB,       // [1024][2048]  bf16
                  const float*   __restrict__ bias,
                  const int*     __restrict__ smap,
                  const uint8_t* __restrict__ zp,
                  float* __restrict__ out)
{
    __shared__ uint8_t AsmB[TILE_M * TILE_K * 2];   // 8 KiB, row stride 64 B
    __shared__ uint8_t BsmB[TILE_N * TILE_K * 2];   // 8 KiB

    const int tid = threadIdx.x;
    const int nT  = blockIdx.x;   // 0..7
    const int mT  = blockIdx.y;   // 0..255

    // ---- staging: thread covers rows (tid>>2) and (tid>>2)+64, 16-B chunk tid&3
    const int r1 = tid >> 2;
    const int ch = (tid & 3) * 16;                   // byte offset in 64-B k-slab
    const int m1 = mT * TILE_M + r1, m2 = m1 + 64;
    const int b1 = m1 >> 12;                         // tile never crosses batch (4096%128==0)
    const uint8_t* wA1 = wordsB + (size_t)m1 * (kD * 2) + ch;
    const uint8_t* wA2 = wordsB + (size_t)m2 * (kD * 2) + ch;
    const int s1 = smap[m1], s2 = smap[m2];
    const uint8_t* sA1 = (s1 >= 0) ? sentsB + ((size_t)(b1 * kS + s1)) * (kD * 2) + ch : zp + ch;
    const uint8_t* sA2 = (s2 >= 0) ? sentsB + ((size_t)(b1 * kS + s2)) * (kD * 2) + ch : zp + ch;
    const uint8_t* wB1 = WB + (size_t)(nT * TILE_N + r1) * (kK * 2) + ch;
    const uint8_t* wB2 = wB1 + (size_t)64 * (kK * 2);

    const int w = tid >> 6;                          // wave id
    uint8_t* ldsA = AsmB + w * 1024;                 // lane l lands at +l*16
    uint8_t* ldsB = BsmB + w * 1024;

    // ---- compute: 4 waves 2x2, each wave 64x64 = 4x4 mfma 16x16x32 tiles
    const int lane = tid & 63;
    const int wm   = (w & 1) * 64;
    const int wn   = (w >> 1) * 64;
    const int fr   = lane & 15;
    const int quad = lane >> 4;

    f32x4 acc[4][4];
    #pragma unroll
    for (int i = 0; i < 4; ++i)
        #pragma unroll
        for (int j = 0; j < 4; ++j)
            acc[i][j] = (f32x4){0.f, 0.f, 0.f, 0.f};

    auto kstep = [&](const uint8_t* a1, const uint8_t* a2,
                     const uint8_t* b1p, const uint8_t* b2p) {
        __syncthreads();                 // prior frag reads done before DMA overwrite
        async16(a1,  ldsA);
        async16(a2,  ldsA + 4096);
        async16(b1p, ldsB);
        async16(b2p, ldsB + 4096);
        __syncthreads();                 // compiler drains vmcnt before barrier

        bf16x8 af[4], bfv[4];
        #pragma unroll
        for (int mi = 0; mi < 4; ++mi)
            af[mi] = *(const bf16x8*)&AsmB[(wm + mi * 16 + fr) * 64 + quad * 16];
        #pragma unroll
        for (int ni = 0; ni < 4; ++ni)
            bfv[ni] = *(const bf16x8*)&BsmB[(wn + ni * 16 + fr) * 64 + quad * 16];

        #pragma unroll
        for (int mi = 0; mi < 4; ++mi)
            #pragma unroll
            for (int ni = 0; ni < 4; ++ni)
                acc[mi][ni] = __builtin_amdgcn_mfma_f32_16x16x32_bf16(
                    af[mi], bfv[ni], acc[mi][ni], 0, 0, 0);
    };

    // K half 1: words side (k = 0..1023)
    for (int k0 = 0; k0 < kD; k0 += TILE_K)
        kstep(wA1 + k0 * 2, wA2 + k0 * 2, wB1 + k0 * 2, wB2 + k0 * 2);
    // K half 2: sentence side (k = 1024..2047); zp rows read zeros
    for (int k0 = 0; k0 < kD; k0 += TILE_K)
        kstep(sA1 + k0 * 2, sA2 + k0 * 2, wB1 + (kD + k0) * 2, wB2 + (kD + k0) * 2);

    // ---- epilogue: bias + relu, fp32 store
    // C/D layout (verified m89): col = lane&15, row = quad*4 + r
    const int rowBase = mT * TILE_M + wm;
    const int colBase = nT * TILE_N + wn;
    float bv[4];
    #pragma unroll
    for (int ni = 0; ni < 4; ++ni) bv[ni] = bias[colBase + ni * 16 + fr];

    #pragma unroll
    for (int mi = 0; mi < 4; ++mi) {
        #pragma unroll
        for (int ni = 0; ni < 4; ++ni) {
            const int col = colBase + ni * 16 + fr;
            #pragma unroll
            for (int r = 0; r < 4; ++r) {
                const int row = rowBase + mi * 16 + quad * 4 + r;
                float v = acc[mi][ni][r] + bv[ni];
                out[(size_t)row * kN + col] = fmaxf(v, 0.f);
            }
        }
    }
}

// ===================== fallback (R2 kernel, passes at ~377 us) ==============
#define LDS_STRIDE 20
__global__ __launch_bounds__(256)
void wsib_gemm_fb(const float* __restrict__ words, const float* __restrict__ sents,
                  const float* __restrict__ W, const float* __restrict__ bias,
                  const int* __restrict__ smap, float* __restrict__ out)
{
    __shared__ uint32_t Asm[TILE_M * LDS_STRIDE];
    __shared__ uint32_t Bsm[TILE_N * LDS_STRIDE];
    const int tid = threadIdx.x, nT = blockIdx.x, mT = blockIdx.y;
    const int sRow = tid >> 1, half = tid & 1;
    const int mRow = mT * TILE_M + sRow, bIdx = mRow >> 12;
    const float* wsrc = words + (size_t)mRow * kD + half * 16;
    const int sidx = smap[mRow];
    const float* ssrc = (sidx >= 0) ? sents + ((size_t)bIdx * kS + sidx) * kD + half * 16 : nullptr;
    const float* bsrc = W + (size_t)(nT * TILE_N + sRow) * kK + half * 16;
    uint32_t* adst = &Asm[sRow * LDS_STRIDE + half * 8];
    uint32_t* bdst = &Bsm[sRow * LDS_STRIDE + half * 8];
    const int lane = tid & 63, wv = tid >> 6;
    const int wm = (wv & 1) * 64, wn = (wv >> 1) * 64;
    const int fr = lane & 15, quad = lane >> 4;
    f32x4 acc[4][4];
    #pragma unroll
    for (int i = 0; i < 4; ++i)
        #pragma unroll
        for (int j = 0; j < 4; ++j) acc[i][j] = (f32x4){0.f, 0.f, 0.f, 0.f};
    float4 ra[4], rb[4];
    {
        const float4* pa = (const float4*)wsrc; const float4* pb = (const float4*)bsrc;
        #pragma unroll
        for (int i = 0; i < 4; ++i) { ra[i] = pa[i]; rb[i] = pb[i]; }
    }
    for (int k0 = 0; k0 < kK; k0 += TILE_K) {
        uint32_t pa[8], pb[8];
        #pragma unroll
        for (int i = 0; i < 4; ++i) {
            pa[2*i] = pk_bf16x2(ra[i].x, ra[i].y); pa[2*i+1] = pk_bf16x2(ra[i].z, ra[i].w);
            pb[2*i] = pk_bf16x2(rb[i].x, rb[i].y); pb[2*i+1] = pk_bf16x2(rb[i].z, rb[i].w);
        }
        __syncthreads();
        ((uint4*)adst)[0] = make_uint4(pa[0], pa[1], pa[2], pa[3]);
        ((uint4*)adst)[1] = make_uint4(pa[4], pa[5], pa[6], pa[7]);
        ((uint4*)bdst)[0] = make_uint4(pb[0], pb[1], pb[2], pb[3]);
        ((uint4*)bdst)[1] = make_uint4(pb[4], pb[5], pb[6], pb[7]);
        __syncthreads();
        const int k1 = k0 + TILE_K;
        if (k1 < kK) {
            const float* asrc = (k1 < kD) ? (wsrc + k1) : (ssrc ? (ssrc + (k1 - kD)) : nullptr);
            if (asrc) { const float4* p = (const float4*)asrc;
                #pragma unroll
                for (int i = 0; i < 4; ++i) ra[i] = p[i];
            } else {
                #pragma unroll
                for (int i = 0; i < 4; ++i) ra[i] = make_float4(0.f, 0.f, 0.f, 0.f);
            }
            const float4* p = (const float4*)(bsrc + k1);
            #pragma unroll
            for (int i = 0; i < 4; ++i) rb[i] = p[i];
        }
        bf16x8 af[4], bfv[4];
        #pragma unroll
        for (int mi = 0; mi < 4; ++mi)
            af[mi] = *(const bf16x8*)&Asm[(wm + mi * 16 + fr) * LDS_STRIDE + quad * 4];
        #pragma unroll
        for (int ni = 0; ni < 4; ++ni)
            bfv[ni] = *(const bf16x8*)&Bsm[(wn + ni * 16 + fr) * LDS_STRIDE + quad * 4];
        #pragma unroll
        for (int mi = 0; mi < 4; ++mi)
            #pragma unroll
            for (int ni = 0; ni < 4; ++ni)
                acc[mi][ni] = __builtin_amdgcn_mfma_f32_16x16x32_bf16(af[mi], bfv[ni], acc[mi][ni], 0, 0, 0);
    }
    const int rowBase = mT * TILE_M + wm, colBase = nT * TILE_N + wn;
    float bv[4];
    #pragma unroll
    for (int ni = 0; ni < 4; ++ni) bv[ni] = bias[colBase + ni * 16 + fr];
    #pragma unroll
    for (int mi = 0; mi < 4; ++mi)
        #pragma unroll
        for (int ni = 0; ni < 4; ++ni) {
            const int col = colBase + ni * 16 + fr;
            #pragma unroll
            for (int r = 0; r < 4; ++r) {
                const int row = rowBase + mi * 16 + quad * 4 + r;
                out[(size_t)row * kN + col] = fmaxf(acc[mi][ni][r] + bv[ni], 0.f);
            }
        }
}

extern "C" void kernel_launch(void* const* d_in, const int* in_sizes, int n_in,
                              void* d_out, int out_size, void* d_ws, size_t ws_size,
                              hipStream_t stream) {
    const float* words = (const float*)d_in[0];   // [8, 4096, 1024] f32
    const float* sents = (const float*)d_in[1];   // [8, 255, 1024]  f32
    const float* W     = (const float*)d_in[2];   // [1024, 2048]    f32
    const float* bias  = (const float*)d_in[3];   // [1024]          f32
    const int*   smap  = (const int*)d_in[4];     // [8, 4096]       i32
    float* out = (float*)d_out;                   // [8, 4096, 1024] f32

    if (ws_size >= WS_NEED) {
        uint8_t* ws = (uint8_t*)d_ws;
        uint2* wordsB = (uint2*)(ws + WS_WORDS);
        uint2* sentsB = (uint2*)(ws + WS_SENTS);
        uint2* WB     = (uint2*)(ws + WS_W);
        uint32_t* zp  = (uint32_t*)(ws + WS_ZP);
        constexpr size_t totalV4 = ((size_t)kM * kD + (size_t)kB * kS * kD + (size_t)kN * kK) / 4;
        const int cvtBlocks = (int)((totalV4 + 255) / 256);   // 36,856
        cvt_prepass<<<cvtBlocks, 256, 0, stream>>>(
            (const float4*)words, (const float4*)sents, (const float4*)W,
            wordsB, sentsB, WB, zp);
        dim3 grid(kN / TILE_N, kM / TILE_M);      // (8, 256)
        wsib_gemm_bf<<<grid, 256, 0, stream>>>(
            (const uint8_t*)wordsB, (const uint8_t*)sentsB, (const uint8_t*)WB,
            bias, smap, (const uint8_t*)zp, out);
    } else {
        dim3 grid(kN / TILE_N, kM / TILE_M);
        wsib_gemm_fb<<<grid, 256, 0, stream>>>(words, sents, W, bias, smap, out);
    }
}